// Round 4
// baseline (501.352 us; speedup 1.0000x reference)
//
#include <hip/hip_runtime.h>
#include <math.h>

#define HID   256
#define HEADS 8
#define DH    32
#define BATCH 2
#define SEQ   4096
#define NTOK  (BATCH*SEQ)   // 8192

typedef float f32x4 __attribute__((ext_vector_type(4)));
typedef short s16x8 __attribute__((ext_vector_type(8)));
typedef short s16x4 __attribute__((ext_vector_type(4)));
typedef unsigned int u32x2 __attribute__((ext_vector_type(2)));

__device__ __forceinline__ unsigned short bf16_rne(float f) {
  unsigned u = __float_as_uint(f);
  unsigned r = u + 0x7fffu + ((u >> 16) & 1u);
  return (unsigned short)(r >> 16);
}

__device__ __forceinline__ s16x8 cvt_bf16x8(f32x4 a, f32x4 b) {
  s16x8 t;
  t[0] = (short)bf16_rne(a[0]); t[1] = (short)bf16_rne(a[1]);
  t[2] = (short)bf16_rne(a[2]); t[3] = (short)bf16_rne(a[3]);
  t[4] = (short)bf16_rne(b[0]); t[5] = (short)bf16_rne(b[1]);
  t[6] = (short)bf16_rne(b[2]); t[7] = (short)bf16_rne(b[3]);
  return t;
}

// ---------------------------------------------------------------------------
// prep: (a) W -> W^T bf16 (n-major), Wq pre-scaled by 1/(sqrt(32)*ln2) so QK^T
// scores are directly in log2 domain; (b) mask -> packed bf16-pair AND masks:
// pmask[i] covers keys {2i, 2i+1}: low16 = 0xFFFF if key 2i kept, etc.
// ---------------------------------------------------------------------------
__global__ __launch_bounds__(256) void prep_kernel(
    const float* __restrict__ Wq, const float* __restrict__ Wk,
    const float* __restrict__ Wv, const float* __restrict__ Wo,
    const int* __restrict__ mask,
    unsigned short* __restrict__ wT,   // 4 mats, layout [w][n][k]
    unsigned* __restrict__ pmask, float qscale)
{
  int id = blockIdx.x * 256 + threadIdx.x;
  if (id < 4 * 65536) {
    int w = id >> 16;
    int r = id & 65535;
    int n = r >> 8, k = r & 255;
    const float* W = (w == 0) ? Wq : (w == 1) ? Wk : (w == 2) ? Wv : Wo;
    float v = W[k * 256 + n];
    if (w == 0) v *= qscale;
    wT[id] = bf16_rne(v);          // wT[w][n][k], coalesced write
  } else if (id < 4 * 65536 + NTOK / 2) {
    int i = id - 4 * 65536;
    unsigned m0 = mask[2 * i] ? 0xFFFFu : 0u;
    unsigned m1 = mask[2 * i + 1] ? 0xFFFF0000u : 0u;
    pmask[i] = m0 | m1;
  }
}

// ---------------------------------------------------------------------------
// qkv_proj: C = A(8192x256 fp32) @ W + b, bf16 out. z selects q/k/v.
// z==2 (V) writes transposed layout (B,H,D,S) for flash's PV fragments.
// ---------------------------------------------------------------------------
__global__ __launch_bounds__(256) void qkv_proj(
    const float* __restrict__ qin, const float* __restrict__ kin,
    const float* __restrict__ vin,
    const unsigned short* __restrict__ wT,
    const float* __restrict__ bq, const float* __restrict__ bk,
    const float* __restrict__ bv,
    unsigned short* __restrict__ q_ws, unsigned short* __restrict__ k_ws,
    unsigned short* __restrict__ vT_ws, float qscale)
{
  const int z = blockIdx.z;
  const float* A = (z == 0) ? qin : (z == 1) ? kin : vin;
  const unsigned short* W = wT + z * 65536;
  const float* bias = (z == 0) ? bq : (z == 1) ? bk : bv;
  const float bscale = (z == 0) ? qscale : 1.f;

  const int lane = threadIdx.x & 63;
  const int wv = threadIdx.x >> 6;
  const int l16 = lane & 15, q4 = lane >> 4;
  const int M0 = blockIdx.x * 64 + (wv & 1) * 32;
  const int N0 = blockIdx.y * 64 + (wv >> 1) * 32;

  f32x4 acc[2][2] = {};
  for (int k0 = 0; k0 < 256; k0 += 32) {
    s16x8 af[2], wf[2];
#pragma unroll
    for (int i = 0; i < 2; ++i) {
      const float* ap = A + (size_t)(M0 + i * 16 + l16) * 256 + k0 + q4 * 8;
      f32x4 a0 = *(const f32x4*)ap;
      f32x4 a1 = *(const f32x4*)(ap + 4);
      af[i] = cvt_bf16x8(a0, a1);
    }
#pragma unroll
    for (int j = 0; j < 2; ++j)
      wf[j] = *(const s16x8*)(W + (size_t)(N0 + j * 16 + l16) * 256 + k0 + q4 * 8);
#pragma unroll
    for (int i = 0; i < 2; ++i)
#pragma unroll
      for (int j = 0; j < 2; ++j)
        acc[i][j] = __builtin_amdgcn_mfma_f32_16x16x32_bf16(af[i], wf[j], acc[i][j], 0, 0, 0);
  }

#pragma unroll
  for (int j = 0; j < 2; ++j) {
    int n = N0 + j * 16 + l16;
    float bb = bias[n] * bscale;
#pragma unroll
    for (int i = 0; i < 2; ++i) {
      int m0 = M0 + i * 16 + q4 * 4;   // 4 consecutive tokens
      f32x4 c = acc[i][j];
      c[0] += bb; c[1] += bb; c[2] += bb; c[3] += bb;
      if (z < 2) {
        unsigned short* o = (z == 0) ? q_ws : k_ws;
#pragma unroll
        for (int r = 0; r < 4; ++r)
          o[(size_t)(m0 + r) * 256 + n] = bf16_rne(c[r]);
      } else {
        // V^T: vT[((b*8+h)*32+d)*4096 + s], 4 consecutive s -> one 8B store
        int bi = m0 >> 12;
        int s = m0 & 4095;
        int h = n >> 5, d = n & 31;
        unsigned lo = (unsigned)bf16_rne(c[0]) | ((unsigned)bf16_rne(c[1]) << 16);
        unsigned hi = (unsigned)bf16_rne(c[2]) | ((unsigned)bf16_rne(c[3]) << 16);
        unsigned* dst = (unsigned*)(vT_ws + (size_t)((bi * 8 + h) * 32 + d) * 4096 + s);
        dst[0] = lo; dst[1] = hi;
      }
    }
  }
}

// ---------------------------------------------------------------------------
// flash v3: fixed-max softmax + SPLIT-K across waves + register prefetch.
// Block = 4 waves covering 2 q-groups (16 queries each) x 2 key-halves (2048
// keys each). Fixed max makes partials linear: O_tot = O_a + O_b, l likewise.
// K-tile + mask double-buffered in registers (load i+1 before compute i), so
// vmcnt never drains fully. V loads in-tile (hidden behind QK-MFMA + exp2).
// End: one barrier + LDS reduction over the 2 key-halves.
// ---------------------------------------------------------------------------
__global__ __launch_bounds__(256, 4) void flash_kernel(
    const unsigned short* __restrict__ q_ws, const unsigned short* __restrict__ k_ws,
    const unsigned short* __restrict__ vT_ws, const unsigned* __restrict__ pmask,
    unsigned short* __restrict__ wtd)
{
  __shared__ float redO[2][2][16][32];   // [qgrp][khalf][q][d]
  __shared__ float redL[2][2][16];

  const int idx = blockIdx.x;            // 2048 blocks
  const int qt = idx & 127, bh = idx >> 7;
  const int b = bh >> 3, h = bh & 7;
  const int lane = threadIdx.x & 63;
  const int wv = threadIdx.x >> 6;
  const int qg = wv & 1, kh = wv >> 1;
  const int l16 = lane & 15, q4 = lane >> 4;
  const int q0 = qt * 32 + qg * 16;
  const int kbase = kh * 2048;

  s16x8 Qf = *(const s16x8*)(q_ws + (size_t)(b * 4096 + q0 + l16) * 256 + h * 32 + q4 * 8);

  const unsigned short* kp = k_ws + (size_t)b * 4096 * 256 + h * 32 + q4 * 8;
  const unsigned short* vp = vT_ws + (size_t)((b * 8 + h) * 32 + l16) * 4096 + q4 * 4;
  const unsigned* pmp = pmask + b * 2048;

  f32x4 o0 = {0.f, 0.f, 0.f, 0.f}, o1 = {0.f, 0.f, 0.f, 0.f};
  f32x4 l_acc = {0.f, 0.f, 0.f, 0.f};

  // B operand for the l-MFMA: B[k][n] = (n==0) ? 1.0bf : 0
  s16x4 onesb;
  {
    short v1b = (l16 == 0) ? (short)0x3F80 : (short)0;
    onesb[0] = v1b; onesb[1] = v1b; onesb[2] = v1b; onesb[3] = v1b;
  }

  s16x8 kf[2][4];
  u32x2 pm[2][4];

#define LOADK(B, KK) do {                                                      \
    int _k = (KK);                                                             \
    _Pragma("unroll") for (int t = 0; t < 4; ++t)                              \
      kf[B][t] = *(const s16x8*)(kp + (size_t)(_k + t * 16 + l16) * 256);      \
    _Pragma("unroll") for (int t = 0; t < 4; ++t)                              \
      pm[B][t] = *(const u32x2*)(pmp + ((_k + t * 16 + q4 * 4) >> 1));         \
  } while (0)

#define COMPUTE(B, KK) do {                                                    \
    int _k = (KK);                                                             \
    const f32x4 zz = {0.f, 0.f, 0.f, 0.f};                                     \
    f32x4 sc[4];                                                               \
    _Pragma("unroll") for (int t = 0; t < 4; ++t)                              \
      sc[t] = __builtin_amdgcn_mfma_f32_16x16x32_bf16(kf[B][t], Qf, zz, 0, 0, 0); \
    _Pragma("unroll") for (int t = 0; t < 4; ++t) {                            \
      unsigned u0 = __float_as_uint(exp2f(sc[t][0])) + 0x8000u;                \
      unsigned u1 = __float_as_uint(exp2f(sc[t][1])) + 0x8000u;                \
      unsigned u2 = __float_as_uint(exp2f(sc[t][2])) + 0x8000u;                \
      unsigned u3 = __float_as_uint(exp2f(sc[t][3])) + 0x8000u;                \
      u32x2 pk;                                                                \
      pk[0] = __builtin_amdgcn_perm(u1, u0, 0x07060302u) & pm[B][t][0];        \
      pk[1] = __builtin_amdgcn_perm(u3, u2, 0x07060302u) & pm[B][t][1];        \
      s16x4 pf = __builtin_bit_cast(s16x4, pk);                                \
      s16x4 v0 = *(const s16x4*)(vp + _k + t * 16);                            \
      s16x4 v1 = *(const s16x4*)(vp + (size_t)16 * 4096 + _k + t * 16);        \
      o0 = __builtin_amdgcn_mfma_f32_16x16x16bf16_1k(pf, v0, o0, 0, 0, 0);     \
      o1 = __builtin_amdgcn_mfma_f32_16x16x16bf16_1k(pf, v1, o1, 0, 0, 0);     \
      l_acc = __builtin_amdgcn_mfma_f32_16x16x16bf16_1k(pf, onesb, l_acc, 0, 0, 0); \
    }                                                                          \
  } while (0)

  LOADK(0, kbase);
  for (int k0 = kbase; k0 < kbase + 2048; k0 += 128) {
    LOADK(1, k0 + 64);
    COMPUTE(0, k0);
    LOADK(0, (k0 + 128 < kbase + 2048) ? k0 + 128 : kbase);  // wrap: harmless
    COMPUTE(1, k0 + 64);
  }
#undef LOADK
#undef COMPUTE

  // write partials: O rows are queries q4*4+r, d = l16 / l16+16
#pragma unroll
  for (int r = 0; r < 4; ++r) {
    int q = q4 * 4 + r;
    redO[qg][kh][q][l16]      = o0[r];
    redO[qg][kh][q][l16 + 16] = o1[r];
  }
  if (l16 == 0) {
#pragma unroll
    for (int r = 0; r < 4; ++r) redL[qg][kh][q4 * 4 + r] = l_acc[r];
  }
  __syncthreads();

  // 256 threads -> 2 q-groups x 16 q x 32 d, 4 d per thread
  {
    int t = threadIdx.x;
    int qg2 = t >> 7, q = (t >> 3) & 15, d0 = (t & 7) * 4;
    f32x4 a = *(const f32x4*)&redO[qg2][0][q][d0];
    f32x4 c = *(const f32x4*)&redO[qg2][1][q][d0];
    float inv = 1.0f / (redL[qg2][0][q] + redL[qg2][1][q]);
    int token = b * 4096 + qt * 32 + qg2 * 16 + q;
    unsigned lo = (unsigned)bf16_rne((a[0] + c[0]) * inv) |
                  ((unsigned)bf16_rne((a[1] + c[1]) * inv) << 16);
    unsigned hi = (unsigned)bf16_rne((a[2] + c[2]) * inv) |
                  ((unsigned)bf16_rne((a[3] + c[3]) * inv) << 16);
    unsigned* dst = (unsigned*)(wtd + (size_t)token * 256 + h * 32 + d0);
    dst[0] = lo; dst[1] = hi;
  }
}

// ---------------------------------------------------------------------------
// o_proj: out = wtd(bf16) @ Wo + bo, fp32 out.
// ---------------------------------------------------------------------------
__global__ __launch_bounds__(256) void o_proj(
    const unsigned short* __restrict__ wtd, const unsigned short* __restrict__ woT,
    const float* __restrict__ bo, float* __restrict__ out)
{
  const int lane = threadIdx.x & 63;
  const int wv = threadIdx.x >> 6;
  const int l16 = lane & 15, q4 = lane >> 4;
  const int M0 = blockIdx.x * 64 + (wv & 1) * 32;
  const int N0 = blockIdx.y * 64 + (wv >> 1) * 32;

  f32x4 acc[2][2] = {};
  for (int k0 = 0; k0 < 256; k0 += 32) {
    s16x8 af[2], wf[2];
#pragma unroll
    for (int i = 0; i < 2; ++i)
      af[i] = *(const s16x8*)(wtd + (size_t)(M0 + i * 16 + l16) * 256 + k0 + q4 * 8);
#pragma unroll
    for (int j = 0; j < 2; ++j)
      wf[j] = *(const s16x8*)(woT + (size_t)(N0 + j * 16 + l16) * 256 + k0 + q4 * 8);
#pragma unroll
    for (int i = 0; i < 2; ++i)
#pragma unroll
      for (int j = 0; j < 2; ++j)
        acc[i][j] = __builtin_amdgcn_mfma_f32_16x16x32_bf16(af[i], wf[j], acc[i][j], 0, 0, 0);
  }

#pragma unroll
  for (int j = 0; j < 2; ++j) {
    int n = N0 + j * 16 + l16;
    float bb = bo[n];
#pragma unroll
    for (int i = 0; i < 2; ++i) {
      int m0 = M0 + i * 16 + q4 * 4;
#pragma unroll
      for (int r = 0; r < 4; ++r)
        out[(size_t)(m0 + r) * 256 + n] = acc[i][j][r] + bb;
    }
  }
}

// ---------------------------------------------------------------------------
extern "C" void kernel_launch(void* const* d_in, const int* in_sizes, int n_in,
                              void* d_out, int out_size, void* d_ws, size_t ws_size,
                              hipStream_t stream) {
  const float* query = (const float*)d_in[0];
  const float* key   = (const float*)d_in[1];
  const float* value = (const float*)d_in[2];
  const int*   mask  = (const int*)d_in[3];
  const float* Wq = (const float*)d_in[4];
  const float* bq = (const float*)d_in[5];
  const float* Wk = (const float*)d_in[6];
  const float* bk = (const float*)d_in[7];
  const float* Wv = (const float*)d_in[8];
  const float* bv = (const float*)d_in[9];
  const float* Wo = (const float*)d_in[10];
  const float* bo = (const float*)d_in[11];
  float* out = (float*)d_out;

  char* p = (char*)d_ws;
  unsigned short* q_ws  = (unsigned short*)p; p += (size_t)NTOK * HID * 2;
  unsigned short* k_ws  = (unsigned short*)p; p += (size_t)NTOK * HID * 2;
  unsigned short* vT_ws = (unsigned short*)p; p += (size_t)NTOK * HID * 2;
  unsigned short* wtd   = (unsigned short*)p; p += (size_t)NTOK * HID * 2;
  unsigned short* wT    = (unsigned short*)p; p += (size_t)4 * 65536 * 2;
  unsigned* pmask       = (unsigned*)p;       p += (size_t)(NTOK / 2) * 4;

  const float qscale = 1.0f / (sqrtf(32.0f) * logf(2.0f)); // fold softmax scale + log2 domain

  prep_kernel<<<(4 * 65536 + NTOK / 2 + 255) / 256, 256, 0, stream>>>(
      Wq, Wk, Wv, Wo, mask, wT, pmask, qscale);
  qkv_proj<<<dim3(NTOK / 64, HID / 64, 3), 256, 0, stream>>>(
      query, key, value, wT, bq, bk, bv, q_ws, k_ws, vT_ws, qscale);
  flash_kernel<<<dim3(2048), 256, 0, stream>>>(
      q_ws, k_ws, vT_ws, pmask, wtd);
  o_proj<<<dim3(NTOK / 64, HID / 64), 256, 0, stream>>>(
      wtd, wT + 3 * 65536, bo, out);
}

// Round 5
// 453.132 us; speedup vs baseline: 1.1064x; 1.1064x over previous
//
#include <hip/hip_runtime.h>
#include <math.h>

#define HID   256
#define HEADS 8
#define DH    32
#define BATCH 2
#define SEQ   4096
#define NTOK  (BATCH*SEQ)   // 8192

typedef float f32x4 __attribute__((ext_vector_type(4)));
typedef short s16x8 __attribute__((ext_vector_type(8)));
typedef short s16x4 __attribute__((ext_vector_type(4)));
typedef unsigned int u32x2 __attribute__((ext_vector_type(2)));

__device__ __forceinline__ unsigned short bf16_rne(float f) {
  unsigned u = __float_as_uint(f);
  unsigned r = u + 0x7fffu + ((u >> 16) & 1u);
  return (unsigned short)(r >> 16);
}

__device__ __forceinline__ s16x8 cvt_bf16x8(f32x4 a, f32x4 b) {
  s16x8 t;
  t[0] = (short)bf16_rne(a[0]); t[1] = (short)bf16_rne(a[1]);
  t[2] = (short)bf16_rne(a[2]); t[3] = (short)bf16_rne(a[3]);
  t[4] = (short)bf16_rne(b[0]); t[5] = (short)bf16_rne(b[1]);
  t[6] = (short)bf16_rne(b[2]); t[7] = (short)bf16_rne(b[3]);
  return t;
}

// ---------------------------------------------------------------------------
// prep: (a) W -> W^T bf16 (n-major), Wq pre-scaled by 1/(sqrt(32)*ln2) so QK^T
// scores are directly in log2 domain; (b) mask -> packed bf16-pair AND masks.
// ---------------------------------------------------------------------------
__global__ __launch_bounds__(256) void prep_kernel(
    const float* __restrict__ Wq, const float* __restrict__ Wk,
    const float* __restrict__ Wv, const float* __restrict__ Wo,
    const int* __restrict__ mask,
    unsigned short* __restrict__ wT,   // 4 mats, layout [w][n][k]
    unsigned* __restrict__ pmask, float qscale)
{
  int id = blockIdx.x * 256 + threadIdx.x;
  if (id < 4 * 65536) {
    int w = id >> 16;
    int r = id & 65535;
    int n = r >> 8, k = r & 255;
    const float* W = (w == 0) ? Wq : (w == 1) ? Wk : (w == 2) ? Wv : Wo;
    float v = W[k * 256 + n];
    if (w == 0) v *= qscale;
    wT[id] = bf16_rne(v);          // wT[w][n][k], coalesced write
  } else if (id < 4 * 65536 + NTOK / 2) {
    int i = id - 4 * 65536;
    unsigned m0 = mask[2 * i] ? 0xFFFFu : 0u;
    unsigned m1 = mask[2 * i + 1] ? 0xFFFF0000u : 0u;
    pmask[i] = m0 | m1;
  }
}

// ---------------------------------------------------------------------------
// qkv_proj: C = A(8192x256 fp32) @ W + b, bf16 out. z selects q/k/v.
// NEW layouts for the flash gather fix:
//   Q : [token][256]                      (unchanged)
//   K : [b][h][s][32]  (64B rows, contiguous in s -> flash K loads 1KB/instr)
//   V : [b][h][s/64][d][s%64]  (4KB d-major tiles -> flash V loads tile-local)
// ---------------------------------------------------------------------------
__global__ __launch_bounds__(256) void qkv_proj(
    const float* __restrict__ qin, const float* __restrict__ kin,
    const float* __restrict__ vin,
    const unsigned short* __restrict__ wT,
    const float* __restrict__ bq, const float* __restrict__ bk,
    const float* __restrict__ bv,
    unsigned short* __restrict__ q_ws, unsigned short* __restrict__ kh_ws,
    unsigned short* __restrict__ vt_ws, float qscale)
{
  const int z = blockIdx.z;
  const float* A = (z == 0) ? qin : (z == 1) ? kin : vin;
  const unsigned short* W = wT + z * 65536;
  const float* bias = (z == 0) ? bq : (z == 1) ? bk : bv;
  const float bscale = (z == 0) ? qscale : 1.f;

  const int lane = threadIdx.x & 63;
  const int wv = threadIdx.x >> 6;
  const int l16 = lane & 15, q4 = lane >> 4;
  const int M0 = blockIdx.x * 64 + (wv & 1) * 32;
  const int N0 = blockIdx.y * 64 + (wv >> 1) * 32;

  f32x4 acc[2][2] = {};
  for (int k0 = 0; k0 < 256; k0 += 32) {
    s16x8 af[2], wf[2];
#pragma unroll
    for (int i = 0; i < 2; ++i) {
      const float* ap = A + (size_t)(M0 + i * 16 + l16) * 256 + k0 + q4 * 8;
      f32x4 a0 = *(const f32x4*)ap;
      f32x4 a1 = *(const f32x4*)(ap + 4);
      af[i] = cvt_bf16x8(a0, a1);
    }
#pragma unroll
    for (int j = 0; j < 2; ++j)
      wf[j] = *(const s16x8*)(W + (size_t)(N0 + j * 16 + l16) * 256 + k0 + q4 * 8);
#pragma unroll
    for (int i = 0; i < 2; ++i)
#pragma unroll
      for (int j = 0; j < 2; ++j)
        acc[i][j] = __builtin_amdgcn_mfma_f32_16x16x32_bf16(af[i], wf[j], acc[i][j], 0, 0, 0);
  }

#pragma unroll
  for (int j = 0; j < 2; ++j) {
    int n = N0 + j * 16 + l16;
    float bb = bias[n] * bscale;
#pragma unroll
    for (int i = 0; i < 2; ++i) {
      int m0 = M0 + i * 16 + q4 * 4;   // 4 consecutive tokens
      f32x4 c = acc[i][j];
      c[0] += bb; c[1] += bb; c[2] += bb; c[3] += bb;
      if (z == 0) {
#pragma unroll
        for (int r = 0; r < 4; ++r)
          q_ws[(size_t)(m0 + r) * 256 + n] = bf16_rne(c[r]);
      } else if (z == 1) {
        // K head-separated: kh[((b*8+h)*4096 + s)*32 + d]
        int bi = m0 >> 12, s = m0 & 4095;
        int h = n >> 5, d = n & 31;
        unsigned short* o = kh_ws + ((size_t)(bi * 8 + h) * 4096 + s) * 32 + d;
#pragma unroll
        for (int r = 0; r < 4; ++r) o[(size_t)r * 32] = bf16_rne(c[r]);
      } else {
        // V tiled d-major: vt[(((b*8+h)*64 + s/64)*32 + d)*64 + s%64]
        int bi = m0 >> 12, s = m0 & 4095;
        int h = n >> 5, d = n & 31;
        int T = s >> 6, sl = s & 63;
        unsigned lo = (unsigned)bf16_rne(c[0]) | ((unsigned)bf16_rne(c[1]) << 16);
        unsigned hi = (unsigned)bf16_rne(c[2]) | ((unsigned)bf16_rne(c[3]) << 16);
        unsigned* dst = (unsigned*)(vt_ws +
            ((size_t)((bi * 8 + h) * 64 + T) * 32 + d) * 64 + sl);
        dst[0] = lo; dst[1] = hi;
      }
    }
  }
}

// ---------------------------------------------------------------------------
// flash v4: fixed-max softmax + split-K + K/V register prefetch, with
// LAYOUT-MATCHED loads: K fragment loads are 1KB contiguous per instruction;
// V fragment loads are 128B-strided within a 4KB L1-resident tile (was 8KB
// stride across the whole sequence -> single-L2-channel hotspot, the r2-r4
// 386us invariant).
// ---------------------------------------------------------------------------
__global__ __launch_bounds__(256, 4) void flash_kernel(
    const unsigned short* __restrict__ q_ws, const unsigned short* __restrict__ kh_ws,
    const unsigned short* __restrict__ vt_ws, const unsigned* __restrict__ pmask,
    unsigned short* __restrict__ wtd)
{
  __shared__ float redO[2][2][16][32];   // [qgrp][khalf][q][d]
  __shared__ float redL[2][2][16];

  const int idx = blockIdx.x;            // 2048 blocks
  const int qt = idx & 127, bh = idx >> 7;
  const int b = bh >> 3, h = bh & 7;
  const int lane = threadIdx.x & 63;
  const int wv = threadIdx.x >> 6;
  const int qg = wv & 1, kh = wv >> 1;
  const int l16 = lane & 15, q4 = lane >> 4;
  const int q0 = qt * 32 + qg * 16;
  const int kbase = kh * 2048;

  s16x8 Qf = *(const s16x8*)(q_ws + (size_t)(b * 4096 + q0 + l16) * 256 + h * 32 + q4 * 8);

  const unsigned short* kp = kh_ws + (size_t)(b * 8 + h) * 4096 * 32 + q4 * 8;
  // V tile base for this (b,h); tile T at +T*2048; element (d, sl) at d*64+sl
  const unsigned short* vb = vt_ws + (size_t)(b * 8 + h) * 64 * 2048
                           + l16 * 64 + q4 * 4;
  const unsigned* pmp = pmask + b * 2048;

  f32x4 o0 = {0.f, 0.f, 0.f, 0.f}, o1 = {0.f, 0.f, 0.f, 0.f};
  f32x4 l_acc = {0.f, 0.f, 0.f, 0.f};

  // B operand for the l-MFMA: B[k][n] = (n==0) ? 1.0bf : 0
  s16x4 onesb;
  {
    short v1b = (l16 == 0) ? (short)0x3F80 : (short)0;
    onesb[0] = v1b; onesb[1] = v1b; onesb[2] = v1b; onesb[3] = v1b;
  }

  s16x8 kf[2][4];
  s16x4 vf[2][4][2];
  u32x2 pm[2][4];

#define LOADT(B, KK) do {                                                      \
    int _k = (KK);                                                             \
    const unsigned short* _tp = vb + (size_t)(_k >> 6) * 2048;                 \
    _Pragma("unroll") for (int t = 0; t < 4; ++t)                              \
      kf[B][t] = *(const s16x8*)(kp + (size_t)(_k + t * 16 + l16) * 32);       \
    _Pragma("unroll") for (int t = 0; t < 4; ++t) {                            \
      vf[B][t][0] = *(const s16x4*)(_tp + t * 16);                             \
      vf[B][t][1] = *(const s16x4*)(_tp + 16 * 64 + t * 16);                   \
    }                                                                          \
    _Pragma("unroll") for (int t = 0; t < 4; ++t)                              \
      pm[B][t] = *(const u32x2*)(pmp + ((_k + t * 16 + q4 * 4) >> 1));         \
  } while (0)

#define COMPUTE(B) do {                                                        \
    const f32x4 zz = {0.f, 0.f, 0.f, 0.f};                                     \
    f32x4 sc[4];                                                               \
    _Pragma("unroll") for (int t = 0; t < 4; ++t)                              \
      sc[t] = __builtin_amdgcn_mfma_f32_16x16x32_bf16(kf[B][t], Qf, zz, 0, 0, 0); \
    _Pragma("unroll") for (int t = 0; t < 4; ++t) {                            \
      unsigned u0 = __float_as_uint(exp2f(sc[t][0])) + 0x8000u;                \
      unsigned u1 = __float_as_uint(exp2f(sc[t][1])) + 0x8000u;                \
      unsigned u2 = __float_as_uint(exp2f(sc[t][2])) + 0x8000u;                \
      unsigned u3 = __float_as_uint(exp2f(sc[t][3])) + 0x8000u;                \
      u32x2 pk;                                                                \
      pk[0] = __builtin_amdgcn_perm(u1, u0, 0x07060302u) & pm[B][t][0];        \
      pk[1] = __builtin_amdgcn_perm(u3, u2, 0x07060302u) & pm[B][t][1];        \
      s16x4 pf = __builtin_bit_cast(s16x4, pk);                                \
      o0 = __builtin_amdgcn_mfma_f32_16x16x16bf16_1k(pf, vf[B][t][0], o0, 0, 0, 0); \
      o1 = __builtin_amdgcn_mfma_f32_16x16x16bf16_1k(pf, vf[B][t][1], o1, 0, 0, 0); \
      l_acc = __builtin_amdgcn_mfma_f32_16x16x16bf16_1k(pf, onesb, l_acc, 0, 0, 0); \
    }                                                                          \
  } while (0)

  LOADT(0, kbase);
  for (int k0 = kbase; k0 < kbase + 2048; k0 += 128) {
    LOADT(1, k0 + 64);
    COMPUTE(0);
    LOADT(0, (k0 + 128 < kbase + 2048) ? k0 + 128 : kbase);  // wrap: harmless
    COMPUTE(1);
  }
#undef LOADT
#undef COMPUTE

  // write partials: O rows are queries q4*4+r, d = l16 / l16+16
#pragma unroll
  for (int r = 0; r < 4; ++r) {
    int q = q4 * 4 + r;
    redO[qg][kh][q][l16]      = o0[r];
    redO[qg][kh][q][l16 + 16] = o1[r];
  }
  if (l16 == 0) {
#pragma unroll
    for (int r = 0; r < 4; ++r) redL[qg][kh][q4 * 4 + r] = l_acc[r];
  }
  __syncthreads();

  // 256 threads -> 2 q-groups x 16 q x 32 d, 4 d per thread
  {
    int t = threadIdx.x;
    int qg2 = t >> 7, q = (t >> 3) & 15, d0 = (t & 7) * 4;
    f32x4 a = *(const f32x4*)&redO[qg2][0][q][d0];
    f32x4 c = *(const f32x4*)&redO[qg2][1][q][d0];
    float inv = 1.0f / (redL[qg2][0][q] + redL[qg2][1][q]);
    int token = b * 4096 + qt * 32 + qg2 * 16 + q;
    unsigned lo = (unsigned)bf16_rne((a[0] + c[0]) * inv) |
                  ((unsigned)bf16_rne((a[1] + c[1]) * inv) << 16);
    unsigned hi = (unsigned)bf16_rne((a[2] + c[2]) * inv) |
                  ((unsigned)bf16_rne((a[3] + c[3]) * inv) << 16);
    unsigned* dst = (unsigned*)(wtd + (size_t)token * 256 + h * 32 + d0);
    dst[0] = lo; dst[1] = hi;
  }
}

// ---------------------------------------------------------------------------
// o_proj: out = wtd(bf16) @ Wo + bo, fp32 out.
// ---------------------------------------------------------------------------
__global__ __launch_bounds__(256) void o_proj(
    const unsigned short* __restrict__ wtd, const unsigned short* __restrict__ woT,
    const float* __restrict__ bo, float* __restrict__ out)
{
  const int lane = threadIdx.x & 63;
  const int wv = threadIdx.x >> 6;
  const int l16 = lane & 15, q4 = lane >> 4;
  const int M0 = blockIdx.x * 64 + (wv & 1) * 32;
  const int N0 = blockIdx.y * 64 + (wv >> 1) * 32;

  f32x4 acc[2][2] = {};
  for (int k0 = 0; k0 < 256; k0 += 32) {
    s16x8 af[2], wf[2];
#pragma unroll
    for (int i = 0; i < 2; ++i)
      af[i] = *(const s16x8*)(wtd + (size_t)(M0 + i * 16 + l16) * 256 + k0 + q4 * 8);
#pragma unroll
    for (int j = 0; j < 2; ++j)
      wf[j] = *(const s16x8*)(woT + (size_t)(N0 + j * 16 + l16) * 256 + k0 + q4 * 8);
#pragma unroll
    for (int i = 0; i < 2; ++i)
#pragma unroll
      for (int j = 0; j < 2; ++j)
        acc[i][j] = __builtin_amdgcn_mfma_f32_16x16x32_bf16(af[i], wf[j], acc[i][j], 0, 0, 0);
  }

#pragma unroll
  for (int j = 0; j < 2; ++j) {
    int n = N0 + j * 16 + l16;
    float bb = bo[n];
#pragma unroll
    for (int i = 0; i < 2; ++i) {
      int m0 = M0 + i * 16 + q4 * 4;
#pragma unroll
      for (int r = 0; r < 4; ++r)
        out[(size_t)(m0 + r) * 256 + n] = acc[i][j][r] + bb;
    }
  }
}

// ---------------------------------------------------------------------------
extern "C" void kernel_launch(void* const* d_in, const int* in_sizes, int n_in,
                              void* d_out, int out_size, void* d_ws, size_t ws_size,
                              hipStream_t stream) {
  const float* query = (const float*)d_in[0];
  const float* key   = (const float*)d_in[1];
  const float* value = (const float*)d_in[2];
  const int*   mask  = (const int*)d_in[3];
  const float* Wq = (const float*)d_in[4];
  const float* bq = (const float*)d_in[5];
  const float* Wk = (const float*)d_in[6];
  const float* bk = (const float*)d_in[7];
  const float* Wv = (const float*)d_in[8];
  const float* bv = (const float*)d_in[9];
  const float* Wo = (const float*)d_in[10];
  const float* bo = (const float*)d_in[11];
  float* out = (float*)d_out;

  char* p = (char*)d_ws;
  unsigned short* q_ws  = (unsigned short*)p; p += (size_t)NTOK * HID * 2;
  unsigned short* kh_ws = (unsigned short*)p; p += (size_t)NTOK * HID * 2;
  unsigned short* vt_ws = (unsigned short*)p; p += (size_t)NTOK * HID * 2;
  unsigned short* wtd   = (unsigned short*)p; p += (size_t)NTOK * HID * 2;
  unsigned short* wT    = (unsigned short*)p; p += (size_t)4 * 65536 * 2;
  unsigned* pmask       = (unsigned*)p;       p += (size_t)(NTOK / 2) * 4;

  const float qscale = 1.0f / (sqrtf(32.0f) * logf(2.0f)); // fold softmax scale + log2 domain

  prep_kernel<<<(4 * 65536 + NTOK / 2 + 255) / 256, 256, 0, stream>>>(
      Wq, Wk, Wv, Wo, mask, wT, pmask, qscale);
  qkv_proj<<<dim3(NTOK / 64, HID / 64, 3), 256, 0, stream>>>(
      query, key, value, wT, bq, bk, bv, q_ws, kh_ws, vt_ws, qscale);
  flash_kernel<<<dim3(2048), 256, 0, stream>>>(
      q_ws, kh_ws, vt_ws, pmask, wtd);
  o_proj<<<dim3(NTOK / 64, HID / 64), 256, 0, stream>>>(
      wtd, wT + 3 * 65536, bo, out);
}

// Round 6
// 349.718 us; speedup vs baseline: 1.4336x; 1.2957x over previous
//
#include <hip/hip_runtime.h>
#include <math.h>

#define HID   256
#define HEADS 8
#define DH    32
#define BATCH 2
#define SEQ   4096
#define NTOK  (BATCH*SEQ)   // 8192

typedef float f32x4 __attribute__((ext_vector_type(4)));
typedef short s16x8 __attribute__((ext_vector_type(8)));
typedef short s16x4 __attribute__((ext_vector_type(4)));
typedef unsigned int u32x2 __attribute__((ext_vector_type(2)));

__device__ __forceinline__ unsigned short bf16_rne(float f) {
  unsigned u = __float_as_uint(f);
  unsigned r = u + 0x7fffu + ((u >> 16) & 1u);
  return (unsigned short)(r >> 16);
}

__device__ __forceinline__ s16x8 cvt_bf16x8(f32x4 a, f32x4 b) {
  s16x8 t;
  t[0] = (short)bf16_rne(a[0]); t[1] = (short)bf16_rne(a[1]);
  t[2] = (short)bf16_rne(a[2]); t[3] = (short)bf16_rne(a[3]);
  t[4] = (short)bf16_rne(b[0]); t[5] = (short)bf16_rne(b[1]);
  t[6] = (short)bf16_rne(b[2]); t[7] = (short)bf16_rne(b[3]);
  return t;
}

// ---------------------------------------------------------------------------
// prep: W -> W^T bf16 (n-major), Wq pre-scaled by 1/(sqrt(32)*ln2);
// mask -> f32 additive bias (0 / -3e4) for the QK MFMA C-operand.
// ---------------------------------------------------------------------------
__global__ __launch_bounds__(256) void prep_kernel(
    const float* __restrict__ Wq, const float* __restrict__ Wk,
    const float* __restrict__ Wv, const float* __restrict__ Wo,
    const int* __restrict__ mask,
    unsigned short* __restrict__ wT,   // 4 mats, layout [w][n][k]
    float* __restrict__ biasf, float qscale)
{
  int id = blockIdx.x * 256 + threadIdx.x;
  if (id < 4 * 65536) {
    int w = id >> 16;
    int r = id & 65535;
    int n = r >> 8, k = r & 255;
    const float* W = (w == 0) ? Wq : (w == 1) ? Wk : (w == 2) ? Wv : Wo;
    float v = W[k * 256 + n];
    if (w == 0) v *= qscale;
    wT[id] = bf16_rne(v);
  } else if (id < 4 * 65536 + NTOK) {
    int i = id - 4 * 65536;
    biasf[i] = mask[i] ? 0.f : -30000.f;
  }
}

// ---------------------------------------------------------------------------
// qkv_proj: C = A(8192x256 fp32) @ W + b, bf16 out. z selects q/k/v.
//   Q : [token][256]
//   K : [b][h][s][32]           (64B rows; 128-key tile = 8KB contiguous)
//   V : [b][h][s/64][d][s%64]   (d-major 4KB subtiles; 128-key tile = 8KB)
// ---------------------------------------------------------------------------
__global__ __launch_bounds__(256) void qkv_proj(
    const float* __restrict__ qin, const float* __restrict__ kin,
    const float* __restrict__ vin,
    const unsigned short* __restrict__ wT,
    const float* __restrict__ bq, const float* __restrict__ bk,
    const float* __restrict__ bv,
    unsigned short* __restrict__ q_ws, unsigned short* __restrict__ kh_ws,
    unsigned short* __restrict__ vt_ws, float qscale)
{
  const int z = blockIdx.z;
  const float* A = (z == 0) ? qin : (z == 1) ? kin : vin;
  const unsigned short* W = wT + z * 65536;
  const float* bias = (z == 0) ? bq : (z == 1) ? bk : bv;
  const float bscale = (z == 0) ? qscale : 1.f;

  const int lane = threadIdx.x & 63;
  const int wv = threadIdx.x >> 6;
  const int l16 = lane & 15, q4 = lane >> 4;
  const int M0 = blockIdx.x * 64 + (wv & 1) * 32;
  const int N0 = blockIdx.y * 64 + (wv >> 1) * 32;

  f32x4 acc[2][2] = {};
  for (int k0 = 0; k0 < 256; k0 += 32) {
    s16x8 af[2], wf[2];
#pragma unroll
    for (int i = 0; i < 2; ++i) {
      const float* ap = A + (size_t)(M0 + i * 16 + l16) * 256 + k0 + q4 * 8;
      f32x4 a0 = *(const f32x4*)ap;
      f32x4 a1 = *(const f32x4*)(ap + 4);
      af[i] = cvt_bf16x8(a0, a1);
    }
#pragma unroll
    for (int j = 0; j < 2; ++j)
      wf[j] = *(const s16x8*)(W + (size_t)(N0 + j * 16 + l16) * 256 + k0 + q4 * 8);
#pragma unroll
    for (int i = 0; i < 2; ++i)
#pragma unroll
      for (int j = 0; j < 2; ++j)
        acc[i][j] = __builtin_amdgcn_mfma_f32_16x16x32_bf16(af[i], wf[j], acc[i][j], 0, 0, 0);
  }

#pragma unroll
  for (int j = 0; j < 2; ++j) {
    int n = N0 + j * 16 + l16;
    float bb = bias[n] * bscale;
#pragma unroll
    for (int i = 0; i < 2; ++i) {
      int m0 = M0 + i * 16 + q4 * 4;   // 4 consecutive tokens
      f32x4 c = acc[i][j];
      c[0] += bb; c[1] += bb; c[2] += bb; c[3] += bb;
      if (z == 0) {
#pragma unroll
        for (int r = 0; r < 4; ++r)
          q_ws[(size_t)(m0 + r) * 256 + n] = bf16_rne(c[r]);
      } else if (z == 1) {
        int bi = m0 >> 12, s = m0 & 4095;
        int h = n >> 5, d = n & 31;
        unsigned short* o = kh_ws + ((size_t)(bi * 8 + h) * 4096 + s) * 32 + d;
#pragma unroll
        for (int r = 0; r < 4; ++r) o[(size_t)r * 32] = bf16_rne(c[r]);
      } else {
        int bi = m0 >> 12, s = m0 & 4095;
        int h = n >> 5, d = n & 31;
        int T = s >> 6, sl = s & 63;
        unsigned lo = (unsigned)bf16_rne(c[0]) | ((unsigned)bf16_rne(c[1]) << 16);
        unsigned hi = (unsigned)bf16_rne(c[2]) | ((unsigned)bf16_rne(c[3]) << 16);
        unsigned* dst = (unsigned*)(vt_ws +
            ((size_t)((bi * 8 + h) * 64 + T) * 32 + d) * 64 + sl);
        dst[0] = lo; dst[1] = hi;
      }
    }
  }
}

// ---------------------------------------------------------------------------
// flash v6: LDS-tiled. Block = 4 waves x 32 queries = 128 q, full 4096 keys.
// Per 128-key tile: K (8KB) + V (8KB) staged into LDS ONCE per block, all 4
// waves read fragments from LDS -> per-CU L1 traffic drops 16x (this was the
// r2-r5 invariant: ~200KB/tile-advance of redundant per-wave L1 line traffic
// at ~64B/cyc = the 3000+cyc stall behind VALUBusy~22%).
// K LDS rows padded to 34 shorts (2-way reads, free); V rows 130 shorts.
// Mask enters as f32 bias C-operand of the QK MFMA from LDS (broadcast).
// ---------------------------------------------------------------------------
__global__ __launch_bounds__(256, 2) void flash_kernel(
    const unsigned short* __restrict__ q_ws, const unsigned short* __restrict__ kh_ws,
    const unsigned short* __restrict__ vt_ws, const float* __restrict__ biasf,
    unsigned short* __restrict__ wtd)
{
  __shared__ unsigned short Kb[2][128 * 34];
  __shared__ unsigned short Vb[2][32 * 130];
  __shared__ float bias_s[4096];

  const int idx = blockIdx.x;          // 512 = 16 bh * 32 qt
  const int qt = idx & 31, bh = idx >> 5;
  const int b = bh >> 3, h = bh & 7;
  const int tid = threadIdx.x;
  const int lane = tid & 63;
  const int wv = tid >> 6;
  const int l16 = lane & 15, q4 = lane >> 4;
  const int q0 = qt * 128 + wv * 32;

  // stage bias for this batch once (16KB, coalesced)
#pragma unroll
  for (int i = 0; i < 4; ++i) {
    f32x4 v = *(const f32x4*)(biasf + b * 4096 + i * 1024 + tid * 4);
    *(f32x4*)&bias_s[i * 1024 + tid * 4] = v;
  }

  // Q fragments: 2 x 16 queries (one-time strided gather, negligible)
  s16x8 Qf[2];
#pragma unroll
  for (int qh = 0; qh < 2; ++qh)
    Qf[qh] = *(const s16x8*)(q_ws +
        (size_t)(b * 4096 + q0 + qh * 16 + l16) * 256 + h * 32 + q4 * 8);

  const unsigned short* Ksrc = kh_ws + (size_t)(b * 8 + h) * 4096 * 32;  // [s][32]
  const unsigned short* Vsrc = vt_ws + (size_t)(b * 8 + h) * 64 * 2048;  // [T64][32][64]

  // per-thread staging targets (each thread moves 32B of K + 32B of V)
  unsigned short* kdst = &Kb[0][(tid >> 1) * 34 + (tid & 1) * 16];
  unsigned short* vdst = &Vb[0][((tid & 127) >> 2) * 130 + (tid >> 7) * 64 + (tid & 3) * 16];

  f32x4 o[2][2] = {{{0.f,0.f,0.f,0.f},{0.f,0.f,0.f,0.f}},
                   {{0.f,0.f,0.f,0.f},{0.f,0.f,0.f,0.f}}};
  f32x4 l[2] = {{0.f,0.f,0.f,0.f},{0.f,0.f,0.f,0.f}};

  s16x4 onesb;   // B[k][n] = (n==0) ? 1.0bf : 0 for the l-MFMA
  {
    short v1b = (l16 == 0) ? (short)0x3F80 : (short)0;
    onesb[0] = v1b; onesb[1] = v1b; onesb[2] = v1b; onesb[3] = v1b;
  }

  s16x8 kreg[2], vreg[2];

#define STAGE_LOAD(T) do {                                                     \
    const unsigned short* _kg = Ksrc + (size_t)(T) * 4096 + tid * 16;          \
    kreg[0] = *(const s16x8*)_kg; kreg[1] = *(const s16x8*)(_kg + 8);          \
    const unsigned short* _vg = Vsrc + (size_t)(T) * 4096 + tid * 16;          \
    vreg[0] = *(const s16x8*)_vg; vreg[1] = *(const s16x8*)(_vg + 8);          \
  } while (0)

#define STAGE_WRITE(B) do {                                                    \
    *(s16x8*)(kdst + (B) * (128 * 34)) = kreg[0];                              \
    *(s16x8*)(kdst + (B) * (128 * 34) + 8) = kreg[1];                          \
    *(s16x8*)(vdst + (B) * (32 * 130)) = vreg[0];                              \
    *(s16x8*)(vdst + (B) * (32 * 130) + 8) = vreg[1];                          \
  } while (0)

#define COMPUTE(B, T) do {                                                     \
    const unsigned short* KL = &Kb[B][0];                                      \
    const unsigned short* VL = &Vb[B][0];                                      \
    const float* BL = &bias_s[(T) * 128];                                      \
    _Pragma("unroll") for (int t = 0; t < 8; ++t) {                            \
      f32x4 bias4 = *(const f32x4*)(BL + t * 16 + q4 * 4);                     \
      s16x8 kf = *(const s16x8*)(KL + (t * 16 + l16) * 34 + q4 * 8);           \
      f32x4 sc0 = __builtin_amdgcn_mfma_f32_16x16x32_bf16(kf, Qf[0], bias4, 0, 0, 0); \
      f32x4 sc1 = __builtin_amdgcn_mfma_f32_16x16x32_bf16(kf, Qf[1], bias4, 0, 0, 0); \
      unsigned a0 = __float_as_uint(exp2f(sc0[0])) + 0x8000u;                  \
      unsigned a1 = __float_as_uint(exp2f(sc0[1])) + 0x8000u;                  \
      unsigned a2 = __float_as_uint(exp2f(sc0[2])) + 0x8000u;                  \
      unsigned a3 = __float_as_uint(exp2f(sc0[3])) + 0x8000u;                  \
      unsigned c0 = __float_as_uint(exp2f(sc1[0])) + 0x8000u;                  \
      unsigned c1 = __float_as_uint(exp2f(sc1[1])) + 0x8000u;                  \
      unsigned c2 = __float_as_uint(exp2f(sc1[2])) + 0x8000u;                  \
      unsigned c3 = __float_as_uint(exp2f(sc1[3])) + 0x8000u;                  \
      u32x2 pk0, pk1;                                                          \
      pk0[0] = __builtin_amdgcn_perm(a1, a0, 0x07060302u);                     \
      pk0[1] = __builtin_amdgcn_perm(a3, a2, 0x07060302u);                     \
      pk1[0] = __builtin_amdgcn_perm(c1, c0, 0x07060302u);                     \
      pk1[1] = __builtin_amdgcn_perm(c3, c2, 0x07060302u);                     \
      s16x4 pf0 = __builtin_bit_cast(s16x4, pk0);                              \
      s16x4 pf1 = __builtin_bit_cast(s16x4, pk1);                              \
      s16x4 vf0 = *(const s16x4*)(VL + l16 * 130 + t * 16 + q4 * 4);           \
      s16x4 vf1 = *(const s16x4*)(VL + (l16 + 16) * 130 + t * 16 + q4 * 4);    \
      o[0][0] = __builtin_amdgcn_mfma_f32_16x16x16bf16_1k(pf0, vf0, o[0][0], 0, 0, 0); \
      o[0][1] = __builtin_amdgcn_mfma_f32_16x16x16bf16_1k(pf0, vf1, o[0][1], 0, 0, 0); \
      o[1][0] = __builtin_amdgcn_mfma_f32_16x16x16bf16_1k(pf1, vf0, o[1][0], 0, 0, 0); \
      o[1][1] = __builtin_amdgcn_mfma_f32_16x16x16bf16_1k(pf1, vf1, o[1][1], 0, 0, 0); \
      l[0] = __builtin_amdgcn_mfma_f32_16x16x16bf16_1k(pf0, onesb, l[0], 0, 0, 0); \
      l[1] = __builtin_amdgcn_mfma_f32_16x16x16bf16_1k(pf1, onesb, l[1], 0, 0, 0); \
    }                                                                          \
  } while (0)

  STAGE_LOAD(0);
  STAGE_WRITE(0);
  STAGE_LOAD(1);
  __syncthreads();

  for (int T = 0; T < 32; ++T) {
    COMPUTE(T & 1, T);
    if (T + 1 < 32) {
      __syncthreads();                  // all waves done reading buf[(T+1)&1]
      STAGE_WRITE((T + 1) & 1);
      if (T + 2 < 32) STAGE_LOAD(T + 2);
      __syncthreads();                  // staged tile visible to all waves
    }
  }
#undef STAGE_LOAD
#undef STAGE_WRITE
#undef COMPUTE

  // epilogue: l(q) lives in D[q][0] (lane q4*16, reg r); normalize + store
  unsigned short* op = wtd + (size_t)(b * 4096 + q0) * 256 + h * 32;
#pragma unroll
  for (int qh = 0; qh < 2; ++qh)
#pragma unroll
    for (int r = 0; r < 4; ++r) {
      float lr = __shfl(l[qh][r], q4 * 16, 64);
      float inv = 1.0f / lr;
      int q = qh * 16 + q4 * 4 + r;
      op[(size_t)q * 256 + l16]      = bf16_rne(o[qh][0][r] * inv);
      op[(size_t)q * 256 + l16 + 16] = bf16_rne(o[qh][1][r] * inv);
    }
}

// ---------------------------------------------------------------------------
// o_proj: out = wtd(bf16) @ Wo + bo, fp32 out.
// ---------------------------------------------------------------------------
__global__ __launch_bounds__(256) void o_proj(
    const unsigned short* __restrict__ wtd, const unsigned short* __restrict__ woT,
    const float* __restrict__ bo, float* __restrict__ out)
{
  const int lane = threadIdx.x & 63;
  const int wv = threadIdx.x >> 6;
  const int l16 = lane & 15, q4 = lane >> 4;
  const int M0 = blockIdx.x * 64 + (wv & 1) * 32;
  const int N0 = blockIdx.y * 64 + (wv >> 1) * 32;

  f32x4 acc[2][2] = {};
  for (int k0 = 0; k0 < 256; k0 += 32) {
    s16x8 af[2], wf[2];
#pragma unroll
    for (int i = 0; i < 2; ++i)
      af[i] = *(const s16x8*)(wtd + (size_t)(M0 + i * 16 + l16) * 256 + k0 + q4 * 8);
#pragma unroll
    for (int j = 0; j < 2; ++j)
      wf[j] = *(const s16x8*)(woT + (size_t)(N0 + j * 16 + l16) * 256 + k0 + q4 * 8);
#pragma unroll
    for (int i = 0; i < 2; ++i)
#pragma unroll
      for (int j = 0; j < 2; ++j)
        acc[i][j] = __builtin_amdgcn_mfma_f32_16x16x32_bf16(af[i], wf[j], acc[i][j], 0, 0, 0);
  }

#pragma unroll
  for (int j = 0; j < 2; ++j) {
    int n = N0 + j * 16 + l16;
    float bb = bo[n];
#pragma unroll
    for (int i = 0; i < 2; ++i) {
      int m0 = M0 + i * 16 + q4 * 4;
#pragma unroll
      for (int r = 0; r < 4; ++r)
        out[(size_t)(m0 + r) * 256 + n] = acc[i][j][r] + bb;
    }
  }
}

// ---------------------------------------------------------------------------
extern "C" void kernel_launch(void* const* d_in, const int* in_sizes, int n_in,
                              void* d_out, int out_size, void* d_ws, size_t ws_size,
                              hipStream_t stream) {
  const float* query = (const float*)d_in[0];
  const float* key   = (const float*)d_in[1];
  const float* value = (const float*)d_in[2];
  const int*   mask  = (const int*)d_in[3];
  const float* Wq = (const float*)d_in[4];
  const float* bq = (const float*)d_in[5];
  const float* Wk = (const float*)d_in[6];
  const float* bk = (const float*)d_in[7];
  const float* Wv = (const float*)d_in[8];
  const float* bv = (const float*)d_in[9];
  const float* Wo = (const float*)d_in[10];
  const float* bo = (const float*)d_in[11];
  float* out = (float*)d_out;

  char* p = (char*)d_ws;
  unsigned short* q_ws  = (unsigned short*)p; p += (size_t)NTOK * HID * 2;
  unsigned short* kh_ws = (unsigned short*)p; p += (size_t)NTOK * HID * 2;
  unsigned short* vt_ws = (unsigned short*)p; p += (size_t)NTOK * HID * 2;
  unsigned short* wtd   = (unsigned short*)p; p += (size_t)NTOK * HID * 2;
  unsigned short* wT    = (unsigned short*)p; p += (size_t)4 * 65536 * 2;
  float* biasf          = (float*)p;          p += (size_t)NTOK * 4;

  const float qscale = 1.0f / (sqrtf(32.0f) * logf(2.0f)); // softmax scale + log2 domain

  prep_kernel<<<(4 * 65536 + NTOK + 255) / 256, 256, 0, stream>>>(
      Wq, Wk, Wv, Wo, mask, wT, biasf, qscale);
  qkv_proj<<<dim3(NTOK / 64, HID / 64, 3), 256, 0, stream>>>(
      query, key, value, wT, bq, bk, bv, q_ws, kh_ws, vt_ws, qscale);
  flash_kernel<<<dim3(512), 256, 0, stream>>>(
      q_ws, kh_ws, vt_ws, biasf, wtd);
  o_proj<<<dim3(NTOK / 64, HID / 64), 256, 0, stream>>>(
      wtd, wT + 3 * 65536, bo, out);
}

// Round 7
// 337.665 us; speedup vs baseline: 1.4848x; 1.0357x over previous
//
#include <hip/hip_runtime.h>
#include <math.h>

#define HID   256
#define HEADS 8
#define DH    32
#define BATCH 2
#define SEQ   4096
#define NTOK  (BATCH*SEQ)   // 8192

typedef float f32x4 __attribute__((ext_vector_type(4)));
typedef short s16x8 __attribute__((ext_vector_type(8)));
typedef short s16x4 __attribute__((ext_vector_type(4)));
typedef unsigned int u32x2 __attribute__((ext_vector_type(2)));

__device__ __forceinline__ unsigned short bf16_rne(float f) {
  unsigned u = __float_as_uint(f);
  unsigned r = u + 0x7fffu + ((u >> 16) & 1u);
  return (unsigned short)(r >> 16);
}

__device__ __forceinline__ s16x8 cvt_bf16x8(f32x4 a, f32x4 b) {
  s16x8 t;
  t[0] = (short)bf16_rne(a[0]); t[1] = (short)bf16_rne(a[1]);
  t[2] = (short)bf16_rne(a[2]); t[3] = (short)bf16_rne(a[3]);
  t[4] = (short)bf16_rne(b[0]); t[5] = (short)bf16_rne(b[1]);
  t[6] = (short)bf16_rne(b[2]); t[7] = (short)bf16_rne(b[3]);
  return t;
}

// ---------------------------------------------------------------------------
// prep: W -> W^T bf16 (n-major), Wq pre-scaled by 1/(sqrt(32)*ln2);
// mask -> f32 additive bias (0 / -3e4) for the QK MFMA C-operand.
// ---------------------------------------------------------------------------
__global__ __launch_bounds__(256) void prep_kernel(
    const float* __restrict__ Wq, const float* __restrict__ Wk,
    const float* __restrict__ Wv, const float* __restrict__ Wo,
    const int* __restrict__ mask,
    unsigned short* __restrict__ wT,   // 4 mats, layout [w][n][k]
    float* __restrict__ biasf, float qscale)
{
  int id = blockIdx.x * 256 + threadIdx.x;
  if (id < 4 * 65536) {
    int w = id >> 16;
    int r = id & 65535;
    int n = r >> 8, k = r & 255;
    const float* W = (w == 0) ? Wq : (w == 1) ? Wk : (w == 2) ? Wv : Wo;
    float v = W[k * 256 + n];
    if (w == 0) v *= qscale;
    wT[id] = bf16_rne(v);
  } else if (id < 4 * 65536 + NTOK) {
    int i = id - 4 * 65536;
    biasf[i] = mask[i] ? 0.f : -30000.f;
  }
}

// ---------------------------------------------------------------------------
// qkv_proj: C = A(8192x256 fp32) @ W + b, bf16 out. z selects q/k/v.
//   Q : [token][256]
//   K : [b][h][s][32]           (64B rows; 128-key tile = 8KB contiguous)
//   V : [b][h][s/64][d][s%64]   (d-major 4KB subtiles; 128-key tile = 8KB)
// ---------------------------------------------------------------------------
__global__ __launch_bounds__(256) void qkv_proj(
    const float* __restrict__ qin, const float* __restrict__ kin,
    const float* __restrict__ vin,
    const unsigned short* __restrict__ wT,
    const float* __restrict__ bq, const float* __restrict__ bk,
    const float* __restrict__ bv,
    unsigned short* __restrict__ q_ws, unsigned short* __restrict__ kh_ws,
    unsigned short* __restrict__ vt_ws, float qscale)
{
  const int z = blockIdx.z;
  const float* A = (z == 0) ? qin : (z == 1) ? kin : vin;
  const unsigned short* W = wT + z * 65536;
  const float* bias = (z == 0) ? bq : (z == 1) ? bk : bv;
  const float bscale = (z == 0) ? qscale : 1.f;

  const int lane = threadIdx.x & 63;
  const int wv = threadIdx.x >> 6;
  const int l16 = lane & 15, q4 = lane >> 4;
  const int M0 = blockIdx.x * 64 + (wv & 1) * 32;
  const int N0 = blockIdx.y * 64 + (wv >> 1) * 32;

  f32x4 acc[2][2] = {};
  for (int k0 = 0; k0 < 256; k0 += 32) {
    s16x8 af[2], wf[2];
#pragma unroll
    for (int i = 0; i < 2; ++i) {
      const float* ap = A + (size_t)(M0 + i * 16 + l16) * 256 + k0 + q4 * 8;
      f32x4 a0 = *(const f32x4*)ap;
      f32x4 a1 = *(const f32x4*)(ap + 4);
      af[i] = cvt_bf16x8(a0, a1);
    }
#pragma unroll
    for (int j = 0; j < 2; ++j)
      wf[j] = *(const s16x8*)(W + (size_t)(N0 + j * 16 + l16) * 256 + k0 + q4 * 8);
#pragma unroll
    for (int i = 0; i < 2; ++i)
#pragma unroll
      for (int j = 0; j < 2; ++j)
        acc[i][j] = __builtin_amdgcn_mfma_f32_16x16x32_bf16(af[i], wf[j], acc[i][j], 0, 0, 0);
  }

#pragma unroll
  for (int j = 0; j < 2; ++j) {
    int n = N0 + j * 16 + l16;
    float bb = bias[n] * bscale;
#pragma unroll
    for (int i = 0; i < 2; ++i) {
      int m0 = M0 + i * 16 + q4 * 4;   // 4 consecutive tokens
      f32x4 c = acc[i][j];
      c[0] += bb; c[1] += bb; c[2] += bb; c[3] += bb;
      if (z == 0) {
#pragma unroll
        for (int r = 0; r < 4; ++r)
          q_ws[(size_t)(m0 + r) * 256 + n] = bf16_rne(c[r]);
      } else if (z == 1) {
        int bi = m0 >> 12, s = m0 & 4095;
        int h = n >> 5, d = n & 31;
        unsigned short* o = kh_ws + ((size_t)(bi * 8 + h) * 4096 + s) * 32 + d;
#pragma unroll
        for (int r = 0; r < 4; ++r) o[(size_t)r * 32] = bf16_rne(c[r]);
      } else {
        int bi = m0 >> 12, s = m0 & 4095;
        int h = n >> 5, d = n & 31;
        int T = s >> 6, sl = s & 63;
        unsigned lo = (unsigned)bf16_rne(c[0]) | ((unsigned)bf16_rne(c[1]) << 16);
        unsigned hi = (unsigned)bf16_rne(c[2]) | ((unsigned)bf16_rne(c[3]) << 16);
        unsigned* dst = (unsigned*)(vt_ws +
            ((size_t)((bi * 8 + h) * 64 + T) * 32 + d) * 64 + sl);
        dst[0] = lo; dst[1] = hi;
      }
    }
  }
}

// ---------------------------------------------------------------------------
// flash v7: LDS 3-buffer RING, ONE barrier per tile.
// r6 bug: STAGE_LOAD was issued between the two barriers, and the compiler's
// mandatory `s_waitcnt vmcnt(0)` before `s_barrier` drained the just-issued
// global loads -> full L2 round-trip exposed per tile (the missing ~60%).
// Now: at iter T -> barrier -> write buf[(T+2)%3] (data loaded during iter
// T-1, long landed) -> issue loads for tile T+3 -> compute buf[T%3]. Loads
// always have a full compute phase in flight before any barrier touches them.
// Buffer hazards: write of buf[(T+2)%3] vs last read at tile T-1 (same buffer
// mod 3) are separated by the iter-T barrier.
// ---------------------------------------------------------------------------
__global__ __launch_bounds__(256, 2) void flash_kernel(
    const unsigned short* __restrict__ q_ws, const unsigned short* __restrict__ kh_ws,
    const unsigned short* __restrict__ vt_ws, const float* __restrict__ biasf,
    unsigned short* __restrict__ wtd)
{
  __shared__ unsigned short Kb[3][128 * 34];
  __shared__ unsigned short Vb[3][32 * 130];
  __shared__ float bias_s[4096];

  const int idx = blockIdx.x;          // 512 = 16 bh * 32 qt
  const int qt = idx & 31, bh = idx >> 5;
  const int b = bh >> 3, h = bh & 7;
  const int tid = threadIdx.x;
  const int lane = tid & 63;
  const int wv = tid >> 6;
  const int l16 = lane & 15, q4 = lane >> 4;
  const int q0 = qt * 128 + wv * 32;

  // stage bias for this batch once (16KB, coalesced)
#pragma unroll
  for (int i = 0; i < 4; ++i) {
    f32x4 v = *(const f32x4*)(biasf + b * 4096 + i * 1024 + tid * 4);
    *(f32x4*)&bias_s[i * 1024 + tid * 4] = v;
  }

  // Q fragments: 2 x 16 queries (one-time strided gather, negligible)
  s16x8 Qf[2];
#pragma unroll
  for (int qh = 0; qh < 2; ++qh)
    Qf[qh] = *(const s16x8*)(q_ws +
        (size_t)(b * 4096 + q0 + qh * 16 + l16) * 256 + h * 32 + q4 * 8);

  const unsigned short* Ksrc = kh_ws + (size_t)(b * 8 + h) * 4096 * 32;  // [s][32]
  const unsigned short* Vsrc = vt_ws + (size_t)(b * 8 + h) * 64 * 2048;  // [T64][32][64]

  // per-thread staging targets (each thread moves 32B of K + 32B of V)
  unsigned short* kdst = &Kb[0][(tid >> 1) * 34 + (tid & 1) * 16];
  unsigned short* vdst = &Vb[0][((tid & 127) >> 2) * 130 + (tid >> 7) * 64 + (tid & 3) * 16];

  f32x4 o[2][2] = {{{0.f,0.f,0.f,0.f},{0.f,0.f,0.f,0.f}},
                   {{0.f,0.f,0.f,0.f},{0.f,0.f,0.f,0.f}}};
  f32x4 l[2] = {{0.f,0.f,0.f,0.f},{0.f,0.f,0.f,0.f}};

  s16x4 onesb;   // B[k][n] = (n==0) ? 1.0bf : 0 for the l-MFMA
  {
    short v1b = (l16 == 0) ? (short)0x3F80 : (short)0;
    onesb[0] = v1b; onesb[1] = v1b; onesb[2] = v1b; onesb[3] = v1b;
  }

  s16x8 kreg[2], vreg[2];

#define STAGE_LOAD(T) do {                                                     \
    const unsigned short* _kg = Ksrc + (size_t)(T) * 4096 + tid * 16;          \
    kreg[0] = *(const s16x8*)_kg; kreg[1] = *(const s16x8*)(_kg + 8);          \
    const unsigned short* _vg = Vsrc + (size_t)(T) * 4096 + tid * 16;          \
    vreg[0] = *(const s16x8*)_vg; vreg[1] = *(const s16x8*)(_vg + 8);          \
  } while (0)

#define STAGE_WRITE(B) do {                                                    \
    *(s16x8*)(kdst + (B) * (128 * 34)) = kreg[0];                              \
    *(s16x8*)(kdst + (B) * (128 * 34) + 8) = kreg[1];                          \
    *(s16x8*)(vdst + (B) * (32 * 130)) = vreg[0];                              \
    *(s16x8*)(vdst + (B) * (32 * 130) + 8) = vreg[1];                          \
  } while (0)

#define COMPUTE(B, T) do {                                                     \
    const unsigned short* KL = &Kb[B][0];                                      \
    const unsigned short* VL = &Vb[B][0];                                      \
    const float* BL = &bias_s[(T) * 128];                                      \
    _Pragma("unroll") for (int t = 0; t < 8; ++t) {                            \
      f32x4 bias4 = *(const f32x4*)(BL + t * 16 + q4 * 4);                     \
      s16x8 kf = *(const s16x8*)(KL + (t * 16 + l16) * 34 + q4 * 8);           \
      f32x4 sc0 = __builtin_amdgcn_mfma_f32_16x16x32_bf16(kf, Qf[0], bias4, 0, 0, 0); \
      f32x4 sc1 = __builtin_amdgcn_mfma_f32_16x16x32_bf16(kf, Qf[1], bias4, 0, 0, 0); \
      unsigned a0 = __float_as_uint(exp2f(sc0[0])) + 0x8000u;                  \
      unsigned a1 = __float_as_uint(exp2f(sc0[1])) + 0x8000u;                  \
      unsigned a2 = __float_as_uint(exp2f(sc0[2])) + 0x8000u;                  \
      unsigned a3 = __float_as_uint(exp2f(sc0[3])) + 0x8000u;                  \
      unsigned c0 = __float_as_uint(exp2f(sc1[0])) + 0x8000u;                  \
      unsigned c1 = __float_as_uint(exp2f(sc1[1])) + 0x8000u;                  \
      unsigned c2 = __float_as_uint(exp2f(sc1[2])) + 0x8000u;                  \
      unsigned c3 = __float_as_uint(exp2f(sc1[3])) + 0x8000u;                  \
      u32x2 pk0, pk1;                                                          \
      pk0[0] = __builtin_amdgcn_perm(a1, a0, 0x07060302u);                     \
      pk0[1] = __builtin_amdgcn_perm(a3, a2, 0x07060302u);                     \
      pk1[0] = __builtin_amdgcn_perm(c1, c0, 0x07060302u);                     \
      pk1[1] = __builtin_amdgcn_perm(c3, c2, 0x07060302u);                     \
      s16x4 pf0 = __builtin_bit_cast(s16x4, pk0);                              \
      s16x4 pf1 = __builtin_bit_cast(s16x4, pk1);                              \
      s16x4 vf0 = *(const s16x4*)(VL + l16 * 130 + t * 16 + q4 * 4);           \
      s16x4 vf1 = *(const s16x4*)(VL + (l16 + 16) * 130 + t * 16 + q4 * 4);    \
      o[0][0] = __builtin_amdgcn_mfma_f32_16x16x16bf16_1k(pf0, vf0, o[0][0], 0, 0, 0); \
      o[0][1] = __builtin_amdgcn_mfma_f32_16x16x16bf16_1k(pf0, vf1, o[0][1], 0, 0, 0); \
      o[1][0] = __builtin_amdgcn_mfma_f32_16x16x16bf16_1k(pf1, vf0, o[1][0], 0, 0, 0); \
      o[1][1] = __builtin_amdgcn_mfma_f32_16x16x16bf16_1k(pf1, vf1, o[1][1], 0, 0, 0); \
      l[0] = __builtin_amdgcn_mfma_f32_16x16x16bf16_1k(pf0, onesb, l[0], 0, 0, 0); \
      l[1] = __builtin_amdgcn_mfma_f32_16x16x16bf16_1k(pf1, onesb, l[1], 0, 0, 0); \
    }                                                                          \
  } while (0)

  // prologue: fill ring buffers 0,1 and put tile-2 loads in flight
  STAGE_LOAD(0); STAGE_WRITE(0);
  STAGE_LOAD(1); STAGE_WRITE(1);
  STAGE_LOAD(2);

  for (int T = 0; T < 32; ++T) {
    __syncthreads();                     // fences reads of buf[(T+2)%3] (tile T-1)
    if (T + 2 < 32) STAGE_WRITE((T + 2) % 3);   // data from loads issued iter T-1
    if (T + 3 < 32) STAGE_LOAD(T + 3);          // in flight across COMPUTE(T)
    COMPUTE(T % 3, T);
  }
#undef STAGE_LOAD
#undef STAGE_WRITE
#undef COMPUTE

  // epilogue: l(q) lives in D[q][0] (lane q4*16, reg r); normalize + store
  unsigned short* op = wtd + (size_t)(b * 4096 + q0) * 256 + h * 32;
#pragma unroll
  for (int qh = 0; qh < 2; ++qh)
#pragma unroll
    for (int r = 0; r < 4; ++r) {
      float lr = __shfl(l[qh][r], q4 * 16, 64);
      float inv = 1.0f / lr;
      int q = qh * 16 + q4 * 4 + r;
      op[(size_t)q * 256 + l16]      = bf16_rne(o[qh][0][r] * inv);
      op[(size_t)q * 256 + l16 + 16] = bf16_rne(o[qh][1][r] * inv);
    }
}

// ---------------------------------------------------------------------------
// o_proj: out = wtd(bf16) @ Wo + bo, fp32 out.
// ---------------------------------------------------------------------------
__global__ __launch_bounds__(256) void o_proj(
    const unsigned short* __restrict__ wtd, const unsigned short* __restrict__ woT,
    const float* __restrict__ bo, float* __restrict__ out)
{
  const int lane = threadIdx.x & 63;
  const int wv = threadIdx.x >> 6;
  const int l16 = lane & 15, q4 = lane >> 4;
  const int M0 = blockIdx.x * 64 + (wv & 1) * 32;
  const int N0 = blockIdx.y * 64 + (wv >> 1) * 32;

  f32x4 acc[2][2] = {};
  for (int k0 = 0; k0 < 256; k0 += 32) {
    s16x8 af[2], wf[2];
#pragma unroll
    for (int i = 0; i < 2; ++i)
      af[i] = *(const s16x8*)(wtd + (size_t)(M0 + i * 16 + l16) * 256 + k0 + q4 * 8);
#pragma unroll
    for (int j = 0; j < 2; ++j)
      wf[j] = *(const s16x8*)(woT + (size_t)(N0 + j * 16 + l16) * 256 + k0 + q4 * 8);
#pragma unroll
    for (int i = 0; i < 2; ++i)
#pragma unroll
      for (int j = 0; j < 2; ++j)
        acc[i][j] = __builtin_amdgcn_mfma_f32_16x16x32_bf16(af[i], wf[j], acc[i][j], 0, 0, 0);
  }

#pragma unroll
  for (int j = 0; j < 2; ++j) {
    int n = N0 + j * 16 + l16;
    float bb = bo[n];
#pragma unroll
    for (int i = 0; i < 2; ++i) {
      int m0 = M0 + i * 16 + q4 * 4;
#pragma unroll
      for (int r = 0; r < 4; ++r)
        out[(size_t)(m0 + r) * 256 + n] = acc[i][j][r] + bb;
    }
  }
}

// ---------------------------------------------------------------------------
extern "C" void kernel_launch(void* const* d_in, const int* in_sizes, int n_in,
                              void* d_out, int out_size, void* d_ws, size_t ws_size,
                              hipStream_t stream) {
  const float* query = (const float*)d_in[0];
  const float* key   = (const float*)d_in[1];
  const float* value = (const float*)d_in[2];
  const int*   mask  = (const int*)d_in[3];
  const float* Wq = (const float*)d_in[4];
  const float* bq = (const float*)d_in[5];
  const float* Wk = (const float*)d_in[6];
  const float* bk = (const float*)d_in[7];
  const float* Wv = (const float*)d_in[8];
  const float* bv = (const float*)d_in[9];
  const float* Wo = (const float*)d_in[10];
  const float* bo = (const float*)d_in[11];
  float* out = (float*)d_out;

  char* p = (char*)d_ws;
  unsigned short* q_ws  = (unsigned short*)p; p += (size_t)NTOK * HID * 2;
  unsigned short* kh_ws = (unsigned short*)p; p += (size_t)NTOK * HID * 2;
  unsigned short* vt_ws = (unsigned short*)p; p += (size_t)NTOK * HID * 2;
  unsigned short* wtd   = (unsigned short*)p; p += (size_t)NTOK * HID * 2;
  unsigned short* wT    = (unsigned short*)p; p += (size_t)4 * 65536 * 2;
  float* biasf          = (float*)p;          p += (size_t)NTOK * 4;

  const float qscale = 1.0f / (sqrtf(32.0f) * logf(2.0f)); // softmax scale + log2 domain

  prep_kernel<<<(4 * 65536 + NTOK + 255) / 256, 256, 0, stream>>>(
      Wq, Wk, Wv, Wo, mask, wT, biasf, qscale);
  qkv_proj<<<dim3(NTOK / 64, HID / 64, 3), 256, 0, stream>>>(
      query, key, value, wT, bq, bk, bv, q_ws, kh_ws, vt_ws, qscale);
  flash_kernel<<<dim3(512), 256, 0, stream>>>(
      q_ws, kh_ws, vt_ws, biasf, wtd);
  o_proj<<<dim3(NTOK / 64, HID / 64), 256, 0, stream>>>(
      wtd, wT + 3 * 65536, bo, out);
}